// Round 16
// baseline (80.964 us; speedup 1.0000x reference)
//
#include <hip/hip_runtime.h>
#include <math.h>

static constexpr int TB = 64;   // batch
static constexpr int LL = 32;   // labels
static constexpr int SS = 256;  // max target length
static constexpr int STRIDE_T = TB * LL;  // floats per time step (2048)

// FCC chunking: NCH chunks -> chunk0 (fwd, init), NI interior (fwd+bwd), last (bwd)
static constexpr int NCH = 16;
static constexpr int NI  = NCH - 2;             // 14 interior
static constexpr int NSCAN = 2 + 2 * NI;        // 30 scans per batch

// ---- workspace layout (floats per batch) --------------------------------
// FCC slots (33 floats): 0=a, 1=c, 2j=p_j, 2j+1=q_j (j=1..NI)
static constexpr int OF_FCC  = 0;               // 30*33 = 990
static constexpr int OF_FACF = 992;             // 256 vals + 64 scales
static constexpr int OF_FACB = 1312;            // 256 vals + 64 scales
static constexpr int WSB     = 1632;            // per-batch stride

#define LN2F 0.69314718055994530942f
#define NEGF (-1e30f)
#define SBAR() __builtin_amdgcn_sched_barrier(0)

// raw barrier: waits LDS only (keeps global-load prefetch in flight)
#define BARX() { asm volatile("s_waitcnt lgkmcnt(0)" ::: "memory"); \
                 __builtin_amdgcn_s_barrier(); \
                 asm volatile("" ::: "memory"); }

// ---- DPP / cross-lane helpers ------------------------------------------
template<int CTL>
__device__ __forceinline__ float dpp_f(float x, float oldv) {
  return __int_as_float(__builtin_amdgcn_update_dpp(
      __float_as_int(oldv), __float_as_int(x), CTL, 0xF, 0xF, false));
}
template<int M>
__device__ __forceinline__ int rot_i(int x) {
  return __builtin_amdgcn_update_dpp(0, x, 0x120 + M, 0xF, 0xF, false); // row_ror:M
}

typedef unsigned uint2v __attribute__((ext_vector_type(2)));
__device__ __forceinline__ float xsum16(float x) {  // x[l] + x[l^16]
  uint2v r = __builtin_amdgcn_permlane16_swap(__float_as_uint(x), __float_as_uint(x), false, false);
  return __uint_as_float(r.x) + __uint_as_float(r.y);
}
__device__ __forceinline__ float xsum32(float x) {  // x[l] + x[l^32]
  uint2v r = __builtin_amdgcn_permlane32_swap(__float_as_uint(x), __float_as_uint(x), false, false);
  return __uint_as_float(r.x) + __uint_as_float(r.y);
}
__device__ __forceinline__ float bperm(int addr, float src) {  // pull lane addr>>2
  return __int_as_float(__builtin_amdgcn_ds_bpermute(addr, __float_as_int(src)));
}

// Self-calibrating coefficient load (rot_i matches row_ror:M exactly)
template<int M>
struct Calib {
  __device__ static __forceinline__ void run(const float* trans, int lam, int i, float* Ec) {
    Ec[M] = __expf(trans[i * LL + rot_i<M>(lam)]);
    Calib<M + 1>::run(trans, lam, i, Ec);
  }
};
template<> struct Calib<16> {
  __device__ static __forceinline__ void run(const float*, int, int, float*) {}
};
// Transposed variant: coefficient trans[rot(lam)][i]  (M^T matvec)
template<int M>
struct CalibT {
  __device__ static __forceinline__ void run(const float* trans, int lam, int i, float* Ec) {
    Ec[M] = __expf(trans[rot_i<M>(lam) * LL + i]);
    CalibT<M + 1>::run(trans, lam, i, Ec);
  }
};
template<> struct CalibT<16> {
  __device__ static __forceinline__ void run(const float*, int, int, float*) {}
};

// ---- fused rotate-multiply asm (1 instr per term) -----------------------
#define ROT_MUL(DST, SRC, COEF, ROT) \
  asm("v_mul_f32_dpp %0, %1, %2 row_ror:" #ROT " row_mask:0xf bank_mask:0xf" \
      : "=v"(DST) : "v"(SRC), "v"(COEF))
#define ROT_FMAC(ACC, SRC, COEF, ROT) \
  asm("v_fmac_f32_dpp %0, %1, %2 row_ror:" #ROT " row_mask:0xf bank_mask:0xf" \
      : "+v"(ACC) : "v"(SRC), "v"(COEF))

// matvec over 16-lane rows: 8 indep chains of depth 2, then 3-level tree
#define STEP16(EC) { \
  float a0 = EC[0] * A, a1, a2, a3, a4, a5, a6, a7; \
  ROT_MUL(a1, A, EC[1], 1); ROT_MUL(a2, A, EC[2], 2); ROT_MUL(a3, A, EC[3], 3); \
  ROT_MUL(a4, A, EC[4], 4); ROT_MUL(a5, A, EC[5], 5); ROT_MUL(a6, A, EC[6], 6); \
  ROT_MUL(a7, A, EC[7], 7); \
  ROT_FMAC(a0, A, EC[8], 8);   ROT_FMAC(a1, A, EC[9], 9); \
  ROT_FMAC(a2, A, EC[10], 10); ROT_FMAC(a3, A, EC[11], 11); \
  ROT_FMAC(a4, A, EC[12], 12); ROT_FMAC(a5, A, EC[13], 13); \
  ROT_FMAC(a6, A, EC[14], 14); ROT_FMAC(a7, A, EC[15], 15); \
  part = ((a0 + a1) + (a2 + a3)) + ((a4 + a5) + (a6 + a7)); }

// ======================= FCC (self-feeding, register staging) ============

#define FCC_RENORM() { \
  unsigned uu = (unsigned)__builtin_amdgcn_readfirstlane((int)__float_as_uint(A)); \
  int ex = (int)((uu >> 23) & 255) - 127; \
  A = ldexpf(A, -ex); Kt += ex; }

// coalesced loads of rows t..t+7 (2 rows/instr via rowoff); clamp high
#define LDBLK(R, TBASE) { \
  _Pragma("unroll") for (int k = 0; k < 4; ++k) { \
    int tt = (TBASE) + 2 * k + rowoff; tt = tt > lenm1 ? lenm1 : tt; \
    R[k] = gpl[(size_t)tt * STRIDE_T]; } \
  SBAR(); }
// descending variant: clamp both ends
#define LDBLKD(R, TBASE) { \
  _Pragma("unroll") for (int k = 0; k < 4; ++k) { \
    int tt = (TBASE) + 2 * k + rowoff; \
    tt = tt < 0 ? 0 : (tt > lenm1 ? lenm1 : tt); \
    R[k] = gpl[(size_t)tt * STRIDE_T]; } \
  SBAR(); }

#define FCC_BLOCK8(R) { \
  float eb[8]; \
  _Pragma("unroll") for (int k = 0; k < 4; ++k) { \
    float e_ = __expf(R[k]); \
    eb[2 * k]     = bperm(adE, e_); \
    eb[2 * k + 1] = bperm(adO, e_); } \
  { float part; STEP16(Ec1); A = eb[0] * xsum16(part); } \
  { float part; STEP16(Ec2); A = eb[1] * xsum32(part); } \
  { float part; STEP16(Ec1); A = eb[2] * xsum16(part); } \
  { float part; STEP16(Ec2); A = eb[3] * xsum32(part); } \
  { float part; STEP16(Ec1); A = eb[4] * xsum16(part); } \
  { float part; STEP16(Ec2); A = eb[5] * xsum32(part); } \
  { float part; STEP16(Ec1); A = eb[6] * xsum16(part); } \
  { float part; STEP16(Ec2); A = eb[7] * xsum32(part); } \
  FCC_RENORM(); }

// backward (transpose): consumes rows 7..0; emission multiplies BEFORE matvec
#define FCC_BWDBLK8(R) { \
  float eb[8]; \
  _Pragma("unroll") for (int k = 0; k < 4; ++k) { \
    float e_ = __expf(R[k]); \
    eb[2 * k]     = bperm(adE, e_); \
    eb[2 * k + 1] = bperm(adO, e_); } \
  { A *= eb[7]; float part; STEP16(E1T); A = xsum16(part); } \
  { A *= eb[6]; float part; STEP16(E2T); A = xsum32(part); } \
  { A *= eb[5]; float part; STEP16(E1T); A = xsum16(part); } \
  { A *= eb[4]; float part; STEP16(E2T); A = xsum32(part); } \
  { A *= eb[3]; float part; STEP16(E1T); A = xsum16(part); } \
  { A *= eb[2]; float part; STEP16(E2T); A = xsum32(part); } \
  { A *= eb[1]; float part; STEP16(E1T); A = xsum16(part); } \
  { A *= eb[0]; float part; STEP16(E2T); A = xsum32(part); } \
  FCC_RENORM(); }

// ======================= FAC (raw-row LDS, pipelined chain gather) =======
// Helper stages exp'd emission rows: sE[pb][row][label] (32 floats/row).
// Chain gathers E[tg[j]] via ds_read_b32 — bank = label, LL == 32 banks
// -> conflict-free (PMC-verified: SQ_LDS_BANK_CONFLICT = 0).

#define FAC_BOUNDARY_S() { \
  float maxA = fmaxf(fmaxf(A0, A1), fmaxf(A2, A3)); \
  if (maxA > 0.f) { \
    int ex = (int)((__float_as_uint(maxA) >> 23) & 255) - 127; \
    A0 = ldexpf(A0, -ex); A1 = ldexpf(A1, -ex); \
    A2 = ldexpf(A2, -ex); A3 = ldexpf(A3, -ex); \
    m += (float)ex; \
  } \
  float mp = dpp_f<0x138>(m, NEGF); m = (m == NEGF) ? mp : m; \
  mp = dpp_f<0x138>(m, NEGF);       m = (m == NEGF) ? mp : m; \
  mp = dpp_f<0x138>(m, NEGF); \
  float dlt = fminf(mp - m, 50.0f); \
  Sin = exp2f(dlt); }

#define FACB_BOUNDARY_S() { \
  float maxA = fmaxf(fmaxf(A0, A1), fmaxf(A2, A3)); \
  if (maxA > 0.f) { \
    int ex = (int)((__float_as_uint(maxA) >> 23) & 255) - 127; \
    A0 = ldexpf(A0, -ex); A1 = ldexpf(A1, -ex); \
    A2 = ldexpf(A2, -ex); A3 = ldexpf(A3, -ex); \
    m += (float)ex; \
  } \
  float mp = dpp_f<0x130>(m, NEGF); m = (m == NEGF) ? mp : m; \
  mp = dpp_f<0x130>(m, NEGF);       m = (m == NEGF) ? mp : m; \
  mp = dpp_f<0x130>(m, NEGF); \
  float dlt = fminf(mp - m, 50.0f); \
  Sb = exp2f(dlt); }

// read 8 rows (BASE..BASE+7) x 4 labels into named register bank
#define FRD8(E0, E1, E2, E3, PB, BASE) { \
  _Pragma("unroll") for (int r = 0; r < 8; ++r) { \
    E0[r] = sE[PB][(BASE) + r][tg[0]]; \
    E1[r] = sE[PB][(BASE) + r][tg[1]]; \
    E2[r] = sE[PB][(BASE) + r][tg[2]]; \
    E3[r] = sE[PB][(BASE) + r][tg[3]]; } \
  SBAR(); }

// consume 8 fwd steps from a bank, then boundary renorm
#define FCONS8(E0, E1, E2, E3) { \
  _Pragma("unroll") for (int r = 0; r < 8; ++r) { \
    float c0 = E0[r] * ST[0], c1 = E1[r] * ST[1]; \
    float c2 = E2[r] * ST[2], c3 = E3[r] * ST[3]; \
    float v0 = E0[r] * CM[0], v1 = E1[r] * CM[1]; \
    float v2 = E2[r] * CM[2], v3 = E3[r] * CM[3]; \
    float ap = dpp_f<0x138>(A3, 0.f); /* wave_shr:1 */ \
    float n0 = fmaf(v0 * Sin, ap, c0 * A0); \
    float n1 = fmaf(v1, A0, c1 * A1); \
    float n2 = fmaf(v2, A1, c2 * A2); \
    float n3 = fmaf(v3, A2, c3 * A3); \
    A0 = n0; A1 = n1; A2 = n2; A3 = n3; } \
  FAC_BOUNDARY_S(); }

// consume 8 bwd steps (rows reversed), then boundary renorm
#define BCONS8(E0, E1, E2, E3) { \
  _Pragma("unroll") for (int i = 0; i < 8; ++i) { const int r = 7 - i; \
    float c0 = E0[r] * ST[0], c1 = E1[r] * ST[1]; \
    float c2 = E2[r] * ST[2], c3 = E3[r] * ST[3]; \
    float w0 = E1[r] * CM[0], w1 = E2[r] * CM[1], w2 = E3[r] * CM[2]; \
    float en3 = dpp_f<0x130>(E0[r], 0.f); /* wave_shl:1 */ \
    float w3 = en3 * CM[3]; \
    float an = dpp_f<0x130>(A0, 0.f); \
    float n0 = fmaf(w0, A1, c0 * A0); \
    float n1 = fmaf(w1, A2, c1 * A1); \
    float n2 = fmaf(w2, A3, c2 * A2); \
    float n3 = fmaf(w3 * Sb, an, c3 * A3); \
    A0 = n0; A1 = n1; A2 = n2; A3 = n3; } \
  FACB_BOUNDARY_S(); }

// pipelined 32-step fwd phase: reads of group k+1 overlap consume of group k
#define FACF_PIPE32(PB) { \
  float a0_[8], a1_[8], a2_[8], a3_[8], b0_[8], b1_[8], b2_[8], b3_[8]; \
  FRD8(a0_, a1_, a2_, a3_, PB, 0); \
  FRD8(b0_, b1_, b2_, b3_, PB, 8); \
  FCONS8(a0_, a1_, a2_, a3_); \
  FRD8(a0_, a1_, a2_, a3_, PB, 16); \
  FCONS8(b0_, b1_, b2_, b3_); \
  FRD8(b0_, b1_, b2_, b3_, PB, 24); \
  FCONS8(a0_, a1_, a2_, a3_); \
  FCONS8(b0_, b1_, b2_, b3_); }

// pipelined 32-step bwd phase (groups consumed 3,2,1,0)
#define FACB_PIPE32(PB) { \
  float a0_[8], a1_[8], a2_[8], a3_[8], b0_[8], b1_[8], b2_[8], b3_[8]; \
  FRD8(a0_, a1_, a2_, a3_, PB, 24); \
  FRD8(b0_, b1_, b2_, b3_, PB, 16); \
  BCONS8(a0_, a1_, a2_, a3_); \
  FRD8(a0_, a1_, a2_, a3_, PB, 8); \
  BCONS8(b0_, b1_, b2_, b3_); \
  FRD8(b0_, b1_, b2_, b3_, PB, 0); \
  BCONS8(a0_, a1_, a2_, a3_); \
  BCONS8(b0_, b1_, b2_, b3_); }

// non-pipelined tail (<32 steps, runs once)
#define FSTEPT(R) { \
  float c0 = e0[R] * ST[0], c1 = e1[R] * ST[1]; \
  float c2 = e2[R] * ST[2], c3 = e3[R] * ST[3]; \
  float v0 = e0[R] * CM[0], v1 = e1[R] * CM[1]; \
  float v2 = e2[R] * CM[2], v3 = e3[R] * CM[3]; \
  float ap = dpp_f<0x138>(A3, 0.f); \
  float n0 = fmaf(v0 * Sin, ap, c0 * A0); \
  float n1 = fmaf(v1, A0, c1 * A1); \
  float n2 = fmaf(v2, A1, c2 * A2); \
  float n3 = fmaf(v3, A2, c3 * A3); \
  A0 = n0; A1 = n1; A2 = n2; A3 = n3; }

#define FACF_TAIL32N(PB, CNT) { \
  float e0[8], e1[8], e2[8], e3[8]; \
  _Pragma("unroll") for (int g4 = 0; g4 < 4; ++g4) { \
    if (8 * g4 >= (CNT)) break; \
    FRD8(e0, e1, e2, e3, PB, 8 * g4); \
    _Pragma("unroll") for (int r = 0; r < 8; ++r) { \
      if (8 * g4 + r >= (CNT)) break; \
      FSTEPT(r); } \
    if (8 * g4 + 8 <= (CNT)) { FAC_BOUNDARY_S(); } } }

// helper: stage 32 exp'd rows of phase Q into buffer PB (16 x {load,exp,write})
#define PRODPH(PB, Q) { \
  _Pragma("unroll") for (int k = 0; k < 16; ++k) { \
    int tt = isfwd ? (1 + 32 * (Q) + 2 * k + rowoff) \
                   : (lenm1 - 32 * (Q) - 31 + 2 * k + rowoff); \
    tt = tt < 0 ? 0 : (tt > lenm1 ? lenm1 : tt); \
    float e_ = __expf(gpl[(size_t)tt * STRIDE_T]); \
    sE[PB][2 * k + rowoff][lam1] = e_; } \
  SBAR(); }

// ======================= main kernel ====================================
// grid: [0,128)        = FAC halves (chain wave + 1 helper wave)
//       [128,128+960)  = FCC chunk scans (2 independent waves / block)

extern "C" __global__ __launch_bounds__(128, 1)
void asg_main(const float* __restrict__ trans, const float* __restrict__ inputs,
              const int* __restrict__ targets, const int* __restrict__ ilen,
              const int* __restrict__ tlen, float* __restrict__ ws) {
  const int tid = (int)threadIdx.x;
  const int w = tid >> 6;
  const int l = tid & 63;
  const int lam1 = l & 31;
  const int lam2 = (l & 15) | ((l >> 5) << 4);
  const int rowoff = l >> 5;
  const int bid = (int)blockIdx.x;

  __shared__ float sE[2][32][32];   // raw exp'd emission rows (8 KB)

  if (bid < 2 * TB) {
    // ================= FAC halves ====================================
    const int role = bid >> 6;   // 0 fwd, 1 bwd
    const int b    = bid & 63;
    const int len = ilen[b];
    const int lenm1 = len - 1;
    const int Lsteps = lenm1;
    int nbf = ((Lsteps / 2) + 31) & ~31;   // balanced: round UP to mult of 32
    if (nbf > Lsteps) nbf = (Lsteps / 2) & ~31;
    const int nff = Lsteps - nbf;          // fwd steps (tail ok)
    const bool isfwd = (role == 0);
    const int nsteps = isfwd ? nff : nbf;
    const int nph = (nsteps + 31) >> 5;
    const float* gpl = inputs + (size_t)b * LL + lam1;
    float* P = ws + (size_t)b * WSB;

    if (w == 0) {
      // ---- chain wave ----
      __builtin_amdgcn_s_setprio(1);
      int tg[4];
      #pragma unroll
      for (int q = 0; q < 4; ++q) tg[q] = targets[b * SS + 4 * l + q];
      float ST[4], CM[4];
      #pragma unroll
      for (int q = 0; q < 4; ++q) ST[q] = __expf(trans[tg[q] * LL + tg[q]]);

      if (isfwd) {
        CM[0] = (l == 0) ? 0.f : __expf(trans[tg[0] * LL + targets[b * SS + 4 * l - 1]]);
        #pragma unroll
        for (int q = 1; q < 4; ++q) CM[q] = __expf(trans[tg[q] * LL + tg[q - 1]]);

        float A0 = (l == 0) ? __expf(inputs[(size_t)b * LL + tg[0]]) : 0.f;
        float A1 = 0.f, A2 = 0.f, A3 = 0.f;
        float m  = (l == 0) ? 0.f : NEGF;
        float Sin;
        FAC_BOUNDARY_S();
        for (int p = 0; p < nph; p += 2) {
          BARX();
          { const int rem = nsteps - 32 * p;
            if (rem >= 32) { FACF_PIPE32(0); } else { FACF_TAIL32N(0, rem); } }
          BARX();
          if (p + 1 < nph) {
            const int rem = nsteps - 32 * (p + 1);
            if (rem >= 32) { FACF_PIPE32(1); } else { FACF_TAIL32N(1, rem); }
          }
        }
        P[OF_FACF + 4 * l + 0] = A0;
        P[OF_FACF + 4 * l + 1] = A1;
        P[OF_FACF + 4 * l + 2] = A2;
        P[OF_FACF + 4 * l + 3] = A3;
        P[OF_FACF + 256 + l]   = m;
      } else {
        CM[0] = __expf(trans[tg[1] * LL + tg[0]]);
        CM[1] = __expf(trans[tg[2] * LL + tg[1]]);
        CM[2] = __expf(trans[tg[3] * LL + tg[2]]);
        int tgn3 = (l < 63) ? targets[b * SS + 4 * l + 4] : 0;
        CM[3] = (l < 63) ? __expf(trans[tgn3 * LL + tg[3]]) : 0.f;

        const int tl = tlen[b];
        const int fs = tl - 1;
        float A0 = (4 * l + 0 == fs) ? 1.f : 0.f;
        float A1 = (4 * l + 1 == fs) ? 1.f : 0.f;
        float A2 = (4 * l + 2 == fs) ? 1.f : 0.f;
        float A3 = (4 * l + 3 == fs) ? 1.f : 0.f;
        float m  = (l == (fs >> 2)) ? 0.f : NEGF;
        float Sb;
        FACB_BOUNDARY_S();
        for (int p = 0; p < nph; p += 2) {
          BARX();
          FACB_PIPE32(0);
          BARX();
          if (p + 1 < nph) { FACB_PIPE32(1); }
        }
        P[OF_FACB + 4 * l + 0] = A0;
        P[OF_FACB + 4 * l + 1] = A1;
        P[OF_FACB + 4 * l + 2] = A2;
        P[OF_FACB + 4 * l + 3] = A3;
        P[OF_FACB + 256 + l]   = m;
      }
    } else {
      // ---- helper wave: raw-row staging, 1 phase ahead ----
      PRODPH(0, 0);
      for (int p = 0; p < nph; p += 2) {
        BARX();
        if (p + 1 < nph) { PRODPH(1, p + 1); }
        BARX();
        if (p + 2 < nph) { PRODPH(0, p + 2); }
      }
    }
    return;
  }

  // ================= FCC chunk scans (2 indep waves / block) ===========
  const int cid = bid - 2 * TB;
  const int sid = 2 * cid + w;     // 0..1919
  const int s = sid >> 6;          // scan id 0..NSCAN-1
  const int b = sid & 63;
  const int len = ilen[b];
  const int lenm1 = len - 1;
  const int Lsteps = lenm1;
  int L = ((Lsteps / NCH) + 4) & ~7;           // balanced chunk length
  if ((NCH - 1) * L > Lsteps) L = (Lsteps / NCH) & ~7;
  const int n0 = Lsteps - (NCH - 1) * L;       // chunk0 length (has tail)

  bool isfwd; int t0 = 1, thi = lenm1, nsteps, outslot;
  if (s == 0)      { isfwd = true;  t0 = 1; nsteps = n0; outslot = 0; }
  else if (s == 1) { isfwd = false; thi = lenm1; nsteps = L; outslot = 1; }
  else {
    const int j = s >> 1;                      // 1..NI
    if ((s & 1) == 0) { isfwd = true;  t0 = n0 + (j - 1) * L + 1; nsteps = L; outslot = 2 * j; }
    else              { isfwd = false; thi = n0 + j * L;          nsteps = L; outslot = 2 * j + 1; }
  }
  const float* gpl = inputs + (size_t)b * LL + lam1;
  float* P = ws + (size_t)b * WSB + OF_FCC + outslot * 33;

  const int adE = lam2 * 4;         // even step gather addr
  const int adO = 128 + lam1 * 4;   // odd step gather addr

  if (isfwd) {
    float Ec1[16], Ec2[16];
    Ec1[0] = __expf(trans[lam2 * LL + lam1]);
    Ec2[0] = __expf(trans[lam1 * LL + lam2]);
    Calib<1>::run(trans, lam1, lam2, Ec1);
    Calib<1>::run(trans, lam2, lam1, Ec2);
    float A = (s == 0) ? __expf(inputs[(size_t)b * LL + lam1]) : 1.f;
    int Kt = 0;
    int t = t0;
    const int tend = t0 + nsteps;
    float R0_[4], R1_[4], R2_[4];
    LDBLK(R0_, t); LDBLK(R1_, t + 8); LDBLK(R2_, t + 16);
    for (;;) {
      if (t + 8 > tend) break;
      FCC_BLOCK8(R0_); LDBLK(R0_, t + 24); t += 8;
      if (t + 8 > tend) break;
      FCC_BLOCK8(R1_); LDBLK(R1_, t + 24); t += 8;
      if (t + 8 > tend) break;
      FCC_BLOCK8(R2_); LDBLK(R2_, t + 24); t += 8;
    }
    if (t < tend) {  // tail (<8 steps)
      float RT[4];
      LDBLK(RT, t);
      float eb[8];
      #pragma unroll
      for (int k = 0; k < 4; ++k) {
        float e_ = __expf(RT[k]);
        eb[2 * k]     = bperm(adE, e_);
        eb[2 * k + 1] = bperm(adO, e_);
      }
      #pragma unroll
      for (int q = 0; q < 8; ++q) {
        if (t + q >= tend) break;
        if ((q & 1) == 0) { float part; STEP16(Ec1); A = eb[q] * xsum16(part); }
        else              { float part; STEP16(Ec2); A = eb[q] * xsum32(part); }
      }
    }
    const int par = nsteps & 1;
    const int idx = par ? lam2 : lam1;
    const bool wr = par ? ((l & 16) == 0) : (l < 32);
    if (wr) P[idx] = A;
    if (l == 0) P[32] = (float)Kt;

  } else {
    float E1T[16], E2T[16];
    E1T[0] = __expf(trans[lam1 * LL + lam2]);
    E2T[0] = __expf(trans[lam2 * LL + lam1]);
    CalibT<1>::run(trans, lam1, lam2, E1T);
    CalibT<1>::run(trans, lam2, lam1, E2T);
    float A = 1.f;
    int Kt = 0;
    int th = thi;
    int rem = nsteps;               // multiple of 8
    float R0_[4], R1_[4], R2_[4];
    LDBLKD(R0_, th - 7); LDBLKD(R1_, th - 15); LDBLKD(R2_, th - 23);
    for (;;) {
      if (rem < 8) break;
      FCC_BWDBLK8(R0_); LDBLKD(R0_, th - 31); th -= 8; rem -= 8;
      if (rem < 8) break;
      FCC_BWDBLK8(R1_); LDBLKD(R1_, th - 31); th -= 8; rem -= 8;
      if (rem < 8) break;
      FCC_BWDBLK8(R2_); LDBLKD(R2_, th - 31); th -= 8; rem -= 8;
    }
    if (l < 32) P[lam1] = A;        // L even -> lam1 layout
    if (l == 0) P[32] = (float)Kt;
  }
}

// ======================= combine (1 block per batch, atomic mean) =======

extern "C" __global__ __launch_bounds__(64)
void asg_combineA(const float* __restrict__ ws, float* __restrict__ out) {
  const int b = (int)blockIdx.x;
  const int l = (int)threadIdx.x;
  const float* P = ws + (size_t)b * WSB;

  // ---- FCC: telescoped rank-1 chunk products ----
  float acc = 0.f;
  float Ksum = P[OF_FCC + 0 * 33 + 32];           // Ka
  #pragma unroll
  for (int j = 0; j <= NI; ++j) {
    const int qs = (j == NI) ? 1 : (2 * j + 3);   // q_{j+1}, last = c
    const int ps = (j == 0) ? 0 : (2 * j);        // p_j, first = a
    float qv = (l < 32) ? P[OF_FCC + qs * 33 + l] : 0.f;
    float pv = (l < 32) ? P[OF_FCC + ps * 33 + l] : 0.f;
    float d = qv * pv;
    #pragma unroll
    for (int mm = 1; mm < 64; mm <<= 1) d += __shfl_xor(d, mm);
    acc += __logf(d);
    Ksum += P[OF_FCC + qs * 33 + 32];             // Kq (or Kc)
  }
  #pragma unroll
  for (int j = 1; j <= NI; ++j) {
    float pv = (l < 32) ? P[OF_FCC + 2 * j * 33 + l] : 0.f;
    #pragma unroll
    for (int mm = 1; mm < 64; mm <<= 1) pv += __shfl_xor(pv, mm);
    acc -= __logf(pv);
  }
  float fcc = acc + Ksum * LN2F;

  // ---- FAC: score = sum_s alpha[s] * beta[s] ----
  float pa = P[OF_FACF + 4 * l + 0] * P[OF_FACB + 4 * l + 0]
           + P[OF_FACF + 4 * l + 1] * P[OF_FACB + 4 * l + 1]
           + P[OF_FACF + 4 * l + 2] * P[OF_FACB + 4 * l + 2]
           + P[OF_FACF + 4 * l + 3] * P[OF_FACB + 4 * l + 3];
  float sc = P[OF_FACF + 256 + l] + P[OF_FACB + 256 + l];
  float Ms = sc;
  #pragma unroll
  for (int mm = 1; mm < 64; mm <<= 1) Ms = fmaxf(Ms, __shfl_xor(Ms, mm));
  float pp = pa * exp2f(sc - Ms);
  #pragma unroll
  for (int mm = 1; mm < 64; mm <<= 1) pp += __shfl_xor(pp, mm);
  float fac = __logf(pp) + Ms * LN2F;

  // accumulate the mean directly (out zeroed by memset before launch)
  if (l == 0) atomicAdd(out, (fcc - fac) * (1.0f / TB));
}

// ======================= launcher =======================================

extern "C" void kernel_launch(void* const* d_in, const int* in_sizes, int n_in,
                              void* d_out, int out_size, void* d_ws, size_t ws_size,
                              hipStream_t stream) {
  const float* trans   = (const float*)d_in[0];
  const float* inputs  = (const float*)d_in[1];
  const int*   targets = (const int*)d_in[2];
  const int*   ilen    = (const int*)d_in[3];
  const int*   tlen    = (const int*)d_in[4];
  float* out = (float*)d_out;
  float* ws  = (float*)d_ws;

  hipMemsetAsync(out, 0, sizeof(float), stream);
  // 128 FAC blocks (chain + helper) + 960 FCC blocks (2 scans each)
  asg_main<<<dim3(2 * TB + (NSCAN * TB) / 2), dim3(128), 0, stream>>>(
      trans, inputs, targets, ilen, tlen, ws);
  asg_combineA<<<dim3(TB), dim3(64), 0, stream>>>(ws, out);
}

// Round 17
// 77.636 us; speedup vs baseline: 1.0429x; 1.0429x over previous
//
#include <hip/hip_runtime.h>
#include <math.h>

static constexpr int TB = 64;   // batch
static constexpr int LL = 32;   // labels
static constexpr int SS = 256;  // max target length
static constexpr int STRIDE_T = TB * LL;  // floats per time step (2048)

// FCC chunking: NCH chunks -> chunk0 (fwd, init), NI interior (fwd+bwd), last (bwd)
static constexpr int NCH = 16;
static constexpr int NI  = NCH - 2;             // 14 interior
static constexpr int NSCAN = 2 + 2 * NI;        // 30 scans per batch

// ---- workspace layout (floats per batch) --------------------------------
// FCC slots (33 floats): 0=a, 1=c, 2j=p_j, 2j+1=q_j (j=1..NI)
static constexpr int OF_FCC  = 0;               // 30*33 = 990
static constexpr int OF_FACF = 992;             // 256 vals + 64 scales
static constexpr int OF_FACB = 1312;            // 256 vals + 64 scales
static constexpr int WSB     = 1632;            // per-batch stride
static constexpr int OF_DIFF = TB * WSB;        // per-batch diff (64 floats)

#define LN2F 0.69314718055994530942f
#define NEGF (-1e30f)
#define SBAR() __builtin_amdgcn_sched_barrier(0)

// raw barrier: waits LDS only (keeps global-load prefetch in flight)
#define BARX() { asm volatile("s_waitcnt lgkmcnt(0)" ::: "memory"); \
                 __builtin_amdgcn_s_barrier(); \
                 asm volatile("" ::: "memory"); }

// ---- DPP / cross-lane helpers ------------------------------------------
template<int CTL>
__device__ __forceinline__ float dpp_f(float x, float oldv) {
  return __int_as_float(__builtin_amdgcn_update_dpp(
      __float_as_int(oldv), __float_as_int(x), CTL, 0xF, 0xF, false));
}
template<int M>
__device__ __forceinline__ int rot_i(int x) {
  return __builtin_amdgcn_update_dpp(0, x, 0x120 + M, 0xF, 0xF, false); // row_ror:M
}

typedef unsigned uint2v __attribute__((ext_vector_type(2)));
__device__ __forceinline__ float xsum16(float x) {  // x[l] + x[l^16]
  uint2v r = __builtin_amdgcn_permlane16_swap(__float_as_uint(x), __float_as_uint(x), false, false);
  return __uint_as_float(r.x) + __uint_as_float(r.y);
}
__device__ __forceinline__ float xsum32(float x) {  // x[l] + x[l^32]
  uint2v r = __builtin_amdgcn_permlane32_swap(__float_as_uint(x), __float_as_uint(x), false, false);
  return __uint_as_float(r.x) + __uint_as_float(r.y);
}
__device__ __forceinline__ float bperm(int addr, float src) {  // pull lane addr>>2
  return __int_as_float(__builtin_amdgcn_ds_bpermute(addr, __float_as_int(src)));
}

// Self-calibrating coefficient load (rot_i matches row_ror:M exactly)
template<int M>
struct Calib {
  __device__ static __forceinline__ void run(const float* trans, int lam, int i, float* Ec) {
    Ec[M] = __expf(trans[i * LL + rot_i<M>(lam)]);
    Calib<M + 1>::run(trans, lam, i, Ec);
  }
};
template<> struct Calib<16> {
  __device__ static __forceinline__ void run(const float*, int, int, float*) {}
};
// Transposed variant: coefficient trans[rot(lam)][i]  (M^T matvec)
template<int M>
struct CalibT {
  __device__ static __forceinline__ void run(const float* trans, int lam, int i, float* Ec) {
    Ec[M] = __expf(trans[rot_i<M>(lam) * LL + i]);
    CalibT<M + 1>::run(trans, lam, i, Ec);
  }
};
template<> struct CalibT<16> {
  __device__ static __forceinline__ void run(const float*, int, int, float*) {}
};

// ---- fused rotate-multiply asm (1 instr per term) -----------------------
#define ROT_MUL(DST, SRC, COEF, ROT) \
  asm("v_mul_f32_dpp %0, %1, %2 row_ror:" #ROT " row_mask:0xf bank_mask:0xf" \
      : "=v"(DST) : "v"(SRC), "v"(COEF))
#define ROT_FMAC(ACC, SRC, COEF, ROT) \
  asm("v_fmac_f32_dpp %0, %1, %2 row_ror:" #ROT " row_mask:0xf bank_mask:0xf" \
      : "+v"(ACC) : "v"(SRC), "v"(COEF))

// matvec over 16-lane rows: 8 indep chains of depth 2, then 3-level tree
#define STEP16(EC) { \
  float a0 = EC[0] * A, a1, a2, a3, a4, a5, a6, a7; \
  ROT_MUL(a1, A, EC[1], 1); ROT_MUL(a2, A, EC[2], 2); ROT_MUL(a3, A, EC[3], 3); \
  ROT_MUL(a4, A, EC[4], 4); ROT_MUL(a5, A, EC[5], 5); ROT_MUL(a6, A, EC[6], 6); \
  ROT_MUL(a7, A, EC[7], 7); \
  ROT_FMAC(a0, A, EC[8], 8);   ROT_FMAC(a1, A, EC[9], 9); \
  ROT_FMAC(a2, A, EC[10], 10); ROT_FMAC(a3, A, EC[11], 11); \
  ROT_FMAC(a4, A, EC[12], 12); ROT_FMAC(a5, A, EC[13], 13); \
  ROT_FMAC(a6, A, EC[14], 14); ROT_FMAC(a7, A, EC[15], 15); \
  part = ((a0 + a1) + (a2 + a3)) + ((a4 + a5) + (a6 + a7)); }

// ======================= FCC (self-feeding, register staging) ============

#define FCC_RENORM() { \
  unsigned uu = (unsigned)__builtin_amdgcn_readfirstlane((int)__float_as_uint(A)); \
  int ex = (int)((uu >> 23) & 255) - 127; \
  A = ldexpf(A, -ex); Kt += ex; }

// coalesced loads of rows t..t+7 (2 rows/instr via rowoff); clamp high
#define LDBLK(R, TBASE) { \
  _Pragma("unroll") for (int k = 0; k < 4; ++k) { \
    int tt = (TBASE) + 2 * k + rowoff; tt = tt > lenm1 ? lenm1 : tt; \
    R[k] = gpl[(size_t)tt * STRIDE_T]; } \
  SBAR(); }
// descending variant: clamp both ends
#define LDBLKD(R, TBASE) { \
  _Pragma("unroll") for (int k = 0; k < 4; ++k) { \
    int tt = (TBASE) + 2 * k + rowoff; \
    tt = tt < 0 ? 0 : (tt > lenm1 ? lenm1 : tt); \
    R[k] = gpl[(size_t)tt * STRIDE_T]; } \
  SBAR(); }

#define FCC_BLOCK8(R) { \
  float eb[8]; \
  _Pragma("unroll") for (int k = 0; k < 4; ++k) { \
    float e_ = __expf(R[k]); \
    eb[2 * k]     = bperm(adE, e_); \
    eb[2 * k + 1] = bperm(adO, e_); } \
  { float part; STEP16(Ec1); A = eb[0] * xsum16(part); } \
  { float part; STEP16(Ec2); A = eb[1] * xsum32(part); } \
  { float part; STEP16(Ec1); A = eb[2] * xsum16(part); } \
  { float part; STEP16(Ec2); A = eb[3] * xsum32(part); } \
  { float part; STEP16(Ec1); A = eb[4] * xsum16(part); } \
  { float part; STEP16(Ec2); A = eb[5] * xsum32(part); } \
  { float part; STEP16(Ec1); A = eb[6] * xsum16(part); } \
  { float part; STEP16(Ec2); A = eb[7] * xsum32(part); } \
  FCC_RENORM(); }

// backward (transpose): consumes rows 7..0; emission multiplies BEFORE matvec
#define FCC_BWDBLK8(R) { \
  float eb[8]; \
  _Pragma("unroll") for (int k = 0; k < 4; ++k) { \
    float e_ = __expf(R[k]); \
    eb[2 * k]     = bperm(adE, e_); \
    eb[2 * k + 1] = bperm(adO, e_); } \
  { A *= eb[7]; float part; STEP16(E1T); A = xsum16(part); } \
  { A *= eb[6]; float part; STEP16(E2T); A = xsum32(part); } \
  { A *= eb[5]; float part; STEP16(E1T); A = xsum16(part); } \
  { A *= eb[4]; float part; STEP16(E2T); A = xsum32(part); } \
  { A *= eb[3]; float part; STEP16(E1T); A = xsum16(part); } \
  { A *= eb[2]; float part; STEP16(E2T); A = xsum32(part); } \
  { A *= eb[1]; float part; STEP16(E1T); A = xsum16(part); } \
  { A *= eb[0]; float part; STEP16(E2T); A = xsum32(part); } \
  FCC_RENORM(); }

// ======================= FAC (raw-row LDS, pipelined chain gather) =======
// Helper stages exp'd emission rows: sE[pb][row][label] (32 floats/row).
// Chain gathers E[tg[j]] via ds_read_b32 — bank = label, LL == 32 banks
// -> conflict-free (PMC-verified: SQ_LDS_BANK_CONFLICT = 0).

#define FAC_BOUNDARY_S() { \
  float maxA = fmaxf(fmaxf(A0, A1), fmaxf(A2, A3)); \
  if (maxA > 0.f) { \
    int ex = (int)((__float_as_uint(maxA) >> 23) & 255) - 127; \
    A0 = ldexpf(A0, -ex); A1 = ldexpf(A1, -ex); \
    A2 = ldexpf(A2, -ex); A3 = ldexpf(A3, -ex); \
    m += (float)ex; \
  } \
  float mp = dpp_f<0x138>(m, NEGF); m = (m == NEGF) ? mp : m; \
  mp = dpp_f<0x138>(m, NEGF);       m = (m == NEGF) ? mp : m; \
  mp = dpp_f<0x138>(m, NEGF); \
  float dlt = fminf(mp - m, 50.0f); \
  Sin = exp2f(dlt); }

#define FACB_BOUNDARY_S() { \
  float maxA = fmaxf(fmaxf(A0, A1), fmaxf(A2, A3)); \
  if (maxA > 0.f) { \
    int ex = (int)((__float_as_uint(maxA) >> 23) & 255) - 127; \
    A0 = ldexpf(A0, -ex); A1 = ldexpf(A1, -ex); \
    A2 = ldexpf(A2, -ex); A3 = ldexpf(A3, -ex); \
    m += (float)ex; \
  } \
  float mp = dpp_f<0x130>(m, NEGF); m = (m == NEGF) ? mp : m; \
  mp = dpp_f<0x130>(m, NEGF);       m = (m == NEGF) ? mp : m; \
  mp = dpp_f<0x130>(m, NEGF); \
  float dlt = fminf(mp - m, 50.0f); \
  Sb = exp2f(dlt); }

// read 8 rows (BASE..BASE+7) x 4 labels into named register bank
#define FRD8(E0, E1, E2, E3, PB, BASE) { \
  _Pragma("unroll") for (int r = 0; r < 8; ++r) { \
    E0[r] = sE[PB][(BASE) + r][tg[0]]; \
    E1[r] = sE[PB][(BASE) + r][tg[1]]; \
    E2[r] = sE[PB][(BASE) + r][tg[2]]; \
    E3[r] = sE[PB][(BASE) + r][tg[3]]; } \
  SBAR(); }

// consume 8 fwd steps from a bank, then boundary renorm
#define FCONS8(E0, E1, E2, E3) { \
  _Pragma("unroll") for (int r = 0; r < 8; ++r) { \
    float c0 = E0[r] * ST[0], c1 = E1[r] * ST[1]; \
    float c2 = E2[r] * ST[2], c3 = E3[r] * ST[3]; \
    float v0 = E0[r] * CM[0], v1 = E1[r] * CM[1]; \
    float v2 = E2[r] * CM[2], v3 = E3[r] * CM[3]; \
    float ap = dpp_f<0x138>(A3, 0.f); /* wave_shr:1 */ \
    float n0 = fmaf(v0 * Sin, ap, c0 * A0); \
    float n1 = fmaf(v1, A0, c1 * A1); \
    float n2 = fmaf(v2, A1, c2 * A2); \
    float n3 = fmaf(v3, A2, c3 * A3); \
    A0 = n0; A1 = n1; A2 = n2; A3 = n3; } \
  FAC_BOUNDARY_S(); }

// consume 8 bwd steps (rows reversed), then boundary renorm
#define BCONS8(E0, E1, E2, E3) { \
  _Pragma("unroll") for (int i = 0; i < 8; ++i) { const int r = 7 - i; \
    float c0 = E0[r] * ST[0], c1 = E1[r] * ST[1]; \
    float c2 = E2[r] * ST[2], c3 = E3[r] * ST[3]; \
    float w0 = E1[r] * CM[0], w1 = E2[r] * CM[1], w2 = E3[r] * CM[2]; \
    float en3 = dpp_f<0x130>(E0[r], 0.f); /* wave_shl:1 */ \
    float w3 = en3 * CM[3]; \
    float an = dpp_f<0x130>(A0, 0.f); \
    float n0 = fmaf(w0, A1, c0 * A0); \
    float n1 = fmaf(w1, A2, c1 * A1); \
    float n2 = fmaf(w2, A3, c2 * A2); \
    float n3 = fmaf(w3 * Sb, an, c3 * A3); \
    A0 = n0; A1 = n1; A2 = n2; A3 = n3; } \
  FACB_BOUNDARY_S(); }

// pipelined 32-step fwd phase: reads of group k+1 overlap consume of group k
#define FACF_PIPE32(PB) { \
  float a0_[8], a1_[8], a2_[8], a3_[8], b0_[8], b1_[8], b2_[8], b3_[8]; \
  FRD8(a0_, a1_, a2_, a3_, PB, 0); \
  FRD8(b0_, b1_, b2_, b3_, PB, 8); \
  FCONS8(a0_, a1_, a2_, a3_); \
  FRD8(a0_, a1_, a2_, a3_, PB, 16); \
  FCONS8(b0_, b1_, b2_, b3_); \
  FRD8(b0_, b1_, b2_, b3_, PB, 24); \
  FCONS8(a0_, a1_, a2_, a3_); \
  FCONS8(b0_, b1_, b2_, b3_); }

// pipelined 32-step bwd phase (groups consumed 3,2,1,0)
#define FACB_PIPE32(PB) { \
  float a0_[8], a1_[8], a2_[8], a3_[8], b0_[8], b1_[8], b2_[8], b3_[8]; \
  FRD8(a0_, a1_, a2_, a3_, PB, 24); \
  FRD8(b0_, b1_, b2_, b3_, PB, 16); \
  BCONS8(a0_, a1_, a2_, a3_); \
  FRD8(a0_, a1_, a2_, a3_, PB, 8); \
  BCONS8(b0_, b1_, b2_, b3_); \
  FRD8(b0_, b1_, b2_, b3_, PB, 0); \
  BCONS8(a0_, a1_, a2_, a3_); \
  BCONS8(b0_, b1_, b2_, b3_); }

// non-pipelined tail (<32 steps, runs once)
#define FSTEPT(R) { \
  float c0 = e0[R] * ST[0], c1 = e1[R] * ST[1]; \
  float c2 = e2[R] * ST[2], c3 = e3[R] * ST[3]; \
  float v0 = e0[R] * CM[0], v1 = e1[R] * CM[1]; \
  float v2 = e2[R] * CM[2], v3 = e3[R] * CM[3]; \
  float ap = dpp_f<0x138>(A3, 0.f); \
  float n0 = fmaf(v0 * Sin, ap, c0 * A0); \
  float n1 = fmaf(v1, A0, c1 * A1); \
  float n2 = fmaf(v2, A1, c2 * A2); \
  float n3 = fmaf(v3, A2, c3 * A3); \
  A0 = n0; A1 = n1; A2 = n2; A3 = n3; }

#define FACF_TAIL32N(PB, CNT) { \
  float e0[8], e1[8], e2[8], e3[8]; \
  _Pragma("unroll") for (int g4 = 0; g4 < 4; ++g4) { \
    if (8 * g4 >= (CNT)) break; \
    FRD8(e0, e1, e2, e3, PB, 8 * g4); \
    _Pragma("unroll") for (int r = 0; r < 8; ++r) { \
      if (8 * g4 + r >= (CNT)) break; \
      FSTEPT(r); } \
    if (8 * g4 + 8 <= (CNT)) { FAC_BOUNDARY_S(); } } }

// helper: stage 32 exp'd rows of phase Q into buffer PB (16 x {load,exp,write})
#define PRODPH(PB, Q) { \
  _Pragma("unroll") for (int k = 0; k < 16; ++k) { \
    int tt = isfwd ? (1 + 32 * (Q) + 2 * k + rowoff) \
                   : (lenm1 - 32 * (Q) - 31 + 2 * k + rowoff); \
    tt = tt < 0 ? 0 : (tt > lenm1 ? lenm1 : tt); \
    float e_ = __expf(gpl[(size_t)tt * STRIDE_T]); \
    sE[PB][2 * k + rowoff][lam1] = e_; } \
  SBAR(); }

// ======================= main kernel ====================================
// grid: [0,128)        = FAC halves (chain wave + 1 helper wave)
//       [128,128+960)  = FCC chunk scans (2 independent waves / block)

extern "C" __global__ __launch_bounds__(128, 1)
void asg_main(const float* __restrict__ trans, const float* __restrict__ inputs,
              const int* __restrict__ targets, const int* __restrict__ ilen,
              const int* __restrict__ tlen, float* __restrict__ ws) {
  const int tid = (int)threadIdx.x;
  const int w = tid >> 6;
  const int l = tid & 63;
  const int lam1 = l & 31;
  const int lam2 = (l & 15) | ((l >> 5) << 4);
  const int rowoff = l >> 5;
  const int bid = (int)blockIdx.x;

  __shared__ float sE[2][32][32];   // raw exp'd emission rows (8 KB)

  if (bid < 2 * TB) {
    // ================= FAC halves ====================================
    const int role = bid >> 6;   // 0 fwd, 1 bwd
    const int b    = bid & 63;
    const int len = ilen[b];
    const int lenm1 = len - 1;
    const int Lsteps = lenm1;
    int nbf = ((Lsteps / 2) + 31) & ~31;   // balanced: round UP to mult of 32
    if (nbf > Lsteps) nbf = (Lsteps / 2) & ~31;
    const int nff = Lsteps - nbf;          // fwd steps (tail ok)
    const bool isfwd = (role == 0);
    const int nsteps = isfwd ? nff : nbf;
    const int nph = (nsteps + 31) >> 5;
    const float* gpl = inputs + (size_t)b * LL + lam1;
    float* P = ws + (size_t)b * WSB;

    if (w == 0) {
      // ---- chain wave ----
      __builtin_amdgcn_s_setprio(1);
      int tg[4];
      #pragma unroll
      for (int q = 0; q < 4; ++q) tg[q] = targets[b * SS + 4 * l + q];
      float ST[4], CM[4];
      #pragma unroll
      for (int q = 0; q < 4; ++q) ST[q] = __expf(trans[tg[q] * LL + tg[q]]);

      if (isfwd) {
        CM[0] = (l == 0) ? 0.f : __expf(trans[tg[0] * LL + targets[b * SS + 4 * l - 1]]);
        #pragma unroll
        for (int q = 1; q < 4; ++q) CM[q] = __expf(trans[tg[q] * LL + tg[q - 1]]);

        float A0 = (l == 0) ? __expf(inputs[(size_t)b * LL + tg[0]]) : 0.f;
        float A1 = 0.f, A2 = 0.f, A3 = 0.f;
        float m  = (l == 0) ? 0.f : NEGF;
        float Sin;
        FAC_BOUNDARY_S();
        for (int p = 0; p < nph; p += 2) {
          BARX();
          { const int rem = nsteps - 32 * p;
            if (rem >= 32) { FACF_PIPE32(0); } else { FACF_TAIL32N(0, rem); } }
          BARX();
          if (p + 1 < nph) {
            const int rem = nsteps - 32 * (p + 1);
            if (rem >= 32) { FACF_PIPE32(1); } else { FACF_TAIL32N(1, rem); }
          }
        }
        P[OF_FACF + 4 * l + 0] = A0;
        P[OF_FACF + 4 * l + 1] = A1;
        P[OF_FACF + 4 * l + 2] = A2;
        P[OF_FACF + 4 * l + 3] = A3;
        P[OF_FACF + 256 + l]   = m;
      } else {
        CM[0] = __expf(trans[tg[1] * LL + tg[0]]);
        CM[1] = __expf(trans[tg[2] * LL + tg[1]]);
        CM[2] = __expf(trans[tg[3] * LL + tg[2]]);
        int tgn3 = (l < 63) ? targets[b * SS + 4 * l + 4] : 0;
        CM[3] = (l < 63) ? __expf(trans[tgn3 * LL + tg[3]]) : 0.f;

        const int tl = tlen[b];
        const int fs = tl - 1;
        float A0 = (4 * l + 0 == fs) ? 1.f : 0.f;
        float A1 = (4 * l + 1 == fs) ? 1.f : 0.f;
        float A2 = (4 * l + 2 == fs) ? 1.f : 0.f;
        float A3 = (4 * l + 3 == fs) ? 1.f : 0.f;
        float m  = (l == (fs >> 2)) ? 0.f : NEGF;
        float Sb;
        FACB_BOUNDARY_S();
        for (int p = 0; p < nph; p += 2) {
          BARX();
          FACB_PIPE32(0);
          BARX();
          if (p + 1 < nph) { FACB_PIPE32(1); }
        }
        P[OF_FACB + 4 * l + 0] = A0;
        P[OF_FACB + 4 * l + 1] = A1;
        P[OF_FACB + 4 * l + 2] = A2;
        P[OF_FACB + 4 * l + 3] = A3;
        P[OF_FACB + 256 + l]   = m;
      }
    } else {
      // ---- helper wave: raw-row staging, 1 phase ahead ----
      PRODPH(0, 0);
      for (int p = 0; p < nph; p += 2) {
        BARX();
        if (p + 1 < nph) { PRODPH(1, p + 1); }
        BARX();
        if (p + 2 < nph) { PRODPH(0, p + 2); }
      }
    }
    return;
  }

  // ================= FCC chunk scans (2 indep waves / block) ===========
  const int cid = bid - 2 * TB;
  const int sid = 2 * cid + w;     // 0..1919
  const int s = sid >> 6;          // scan id 0..NSCAN-1
  const int b = sid & 63;
  const int len = ilen[b];
  const int lenm1 = len - 1;
  const int Lsteps = lenm1;
  int L = ((Lsteps / NCH) + 4) & ~7;           // balanced chunk length
  if ((NCH - 1) * L > Lsteps) L = (Lsteps / NCH) & ~7;
  const int n0 = Lsteps - (NCH - 1) * L;       // chunk0 length (has tail)

  bool isfwd; int t0 = 1, thi = lenm1, nsteps, outslot;
  if (s == 0)      { isfwd = true;  t0 = 1; nsteps = n0; outslot = 0; }
  else if (s == 1) { isfwd = false; thi = lenm1; nsteps = L; outslot = 1; }
  else {
    const int j = s >> 1;                      // 1..NI
    if ((s & 1) == 0) { isfwd = true;  t0 = n0 + (j - 1) * L + 1; nsteps = L; outslot = 2 * j; }
    else              { isfwd = false; thi = n0 + j * L;          nsteps = L; outslot = 2 * j + 1; }
  }
  const float* gpl = inputs + (size_t)b * LL + lam1;
  float* P = ws + (size_t)b * WSB + OF_FCC + outslot * 33;

  const int adE = lam2 * 4;         // even step gather addr
  const int adO = 128 + lam1 * 4;   // odd step gather addr

  if (isfwd) {
    float Ec1[16], Ec2[16];
    Ec1[0] = __expf(trans[lam2 * LL + lam1]);
    Ec2[0] = __expf(trans[lam1 * LL + lam2]);
    Calib<1>::run(trans, lam1, lam2, Ec1);
    Calib<1>::run(trans, lam2, lam1, Ec2);
    float A = (s == 0) ? __expf(inputs[(size_t)b * LL + lam1]) : 1.f;
    int Kt = 0;
    int t = t0;
    const int tend = t0 + nsteps;
    float R0_[4], R1_[4], R2_[4];
    LDBLK(R0_, t); LDBLK(R1_, t + 8); LDBLK(R2_, t + 16);
    for (;;) {
      if (t + 8 > tend) break;
      FCC_BLOCK8(R0_); LDBLK(R0_, t + 24); t += 8;
      if (t + 8 > tend) break;
      FCC_BLOCK8(R1_); LDBLK(R1_, t + 24); t += 8;
      if (t + 8 > tend) break;
      FCC_BLOCK8(R2_); LDBLK(R2_, t + 24); t += 8;
    }
    if (t < tend) {  // tail (<8 steps)
      float RT[4];
      LDBLK(RT, t);
      float eb[8];
      #pragma unroll
      for (int k = 0; k < 4; ++k) {
        float e_ = __expf(RT[k]);
        eb[2 * k]     = bperm(adE, e_);
        eb[2 * k + 1] = bperm(adO, e_);
      }
      #pragma unroll
      for (int q = 0; q < 8; ++q) {
        if (t + q >= tend) break;
        if ((q & 1) == 0) { float part; STEP16(Ec1); A = eb[q] * xsum16(part); }
        else              { float part; STEP16(Ec2); A = eb[q] * xsum32(part); }
      }
    }
    const int par = nsteps & 1;
    const int idx = par ? lam2 : lam1;
    const bool wr = par ? ((l & 16) == 0) : (l < 32);
    if (wr) P[idx] = A;
    if (l == 0) P[32] = (float)Kt;

  } else {
    float E1T[16], E2T[16];
    E1T[0] = __expf(trans[lam1 * LL + lam2]);
    E2T[0] = __expf(trans[lam2 * LL + lam1]);
    CalibT<1>::run(trans, lam1, lam2, E1T);
    CalibT<1>::run(trans, lam2, lam1, E2T);
    float A = 1.f;
    int Kt = 0;
    int th = thi;
    int rem = nsteps;               // multiple of 8
    float R0_[4], R1_[4], R2_[4];
    LDBLKD(R0_, th - 7); LDBLKD(R1_, th - 15); LDBLKD(R2_, th - 23);
    for (;;) {
      if (rem < 8) break;
      FCC_BWDBLK8(R0_); LDBLKD(R0_, th - 31); th -= 8; rem -= 8;
      if (rem < 8) break;
      FCC_BWDBLK8(R1_); LDBLKD(R1_, th - 31); th -= 8; rem -= 8;
      if (rem < 8) break;
      FCC_BWDBLK8(R2_); LDBLKD(R2_, th - 31); th -= 8; rem -= 8;
    }
    if (l < 32) P[lam1] = A;        // L even -> lam1 layout
    if (l == 0) P[32] = (float)Kt;
  }
}

// ======================= combine (parallel, 1 block per batch) ==========

extern "C" __global__ __launch_bounds__(64)
void asg_combineA(const float* __restrict__ ws, float* __restrict__ wdiff) {
  const int b = (int)blockIdx.x;
  const int l = (int)threadIdx.x;
  const float* P = ws + (size_t)b * WSB;

  // ---- FCC: telescoped rank-1 chunk products ----
  float acc = 0.f;
  float Ksum = P[OF_FCC + 0 * 33 + 32];           // Ka
  #pragma unroll
  for (int j = 0; j <= NI; ++j) {
    const int qs = (j == NI) ? 1 : (2 * j + 3);   // q_{j+1}, last = c
    const int ps = (j == 0) ? 0 : (2 * j);        // p_j, first = a
    float qv = (l < 32) ? P[OF_FCC + qs * 33 + l] : 0.f;
    float pv = (l < 32) ? P[OF_FCC + ps * 33 + l] : 0.f;
    float d = qv * pv;
    #pragma unroll
    for (int mm = 1; mm < 64; mm <<= 1) d += __shfl_xor(d, mm);
    acc += __logf(d);
    Ksum += P[OF_FCC + qs * 33 + 32];             // Kq (or Kc)
  }
  #pragma unroll
  for (int j = 1; j <= NI; ++j) {
    float pv = (l < 32) ? P[OF_FCC + 2 * j * 33 + l] : 0.f;
    #pragma unroll
    for (int mm = 1; mm < 64; mm <<= 1) pv += __shfl_xor(pv, mm);
    acc -= __logf(pv);
  }
  float fcc = acc + Ksum * LN2F;

  // ---- FAC: score = sum_s alpha[s] * beta[s] ----
  float pa = P[OF_FACF + 4 * l + 0] * P[OF_FACB + 4 * l + 0]
           + P[OF_FACF + 4 * l + 1] * P[OF_FACB + 4 * l + 1]
           + P[OF_FACF + 4 * l + 2] * P[OF_FACB + 4 * l + 2]
           + P[OF_FACF + 4 * l + 3] * P[OF_FACB + 4 * l + 3];
  float sc = P[OF_FACF + 256 + l] + P[OF_FACB + 256 + l];
  float Ms = sc;
  #pragma unroll
  for (int mm = 1; mm < 64; mm <<= 1) Ms = fmaxf(Ms, __shfl_xor(Ms, mm));
  float pp = pa * exp2f(sc - Ms);
  #pragma unroll
  for (int mm = 1; mm < 64; mm <<= 1) pp += __shfl_xor(pp, mm);
  float fac = __logf(pp) + Ms * LN2F;

  if (l == 0) wdiff[b] = fcc - fac;
}

extern "C" __global__ __launch_bounds__(64)
void asg_combineB(const float* __restrict__ wdiff, float* __restrict__ out) {
  const int l = (int)threadIdx.x;
  float d = wdiff[l];
  #pragma unroll
  for (int mm = 1; mm < 64; mm <<= 1) d += __shfl_xor(d, mm);
  if (l == 0) out[0] = d * (1.0f / TB);
}

// ======================= launcher =======================================

extern "C" void kernel_launch(void* const* d_in, const int* in_sizes, int n_in,
                              void* d_out, int out_size, void* d_ws, size_t ws_size,
                              hipStream_t stream) {
  const float* trans   = (const float*)d_in[0];
  const float* inputs  = (const float*)d_in[1];
  const int*   targets = (const int*)d_in[2];
  const int*   ilen    = (const int*)d_in[3];
  const int*   tlen    = (const int*)d_in[4];
  float* out = (float*)d_out;
  float* ws  = (float*)d_ws;

  // 128 FAC blocks (chain + helper) + 960 FCC blocks (2 scans each)
  asg_main<<<dim3(2 * TB + (NSCAN * TB) / 2), dim3(128), 0, stream>>>(
      trans, inputs, targets, ilen, tlen, ws);
  asg_combineA<<<dim3(TB), dim3(64), 0, stream>>>(ws, ws + OF_DIFF);
  asg_combineB<<<dim3(1), dim3(64), 0, stream>>>(ws + OF_DIFF, out);
}